// Round 21
// baseline (101.248 us; speedup 1.0000x reference)
//
#include <hip/hip_runtime.h>
#include <cstdint>
#include <cstddef>

typedef unsigned long long ull;
typedef unsigned short u16;

#define N 8192
#define NWORDS 128          // 8192 / 64
#define NPOST 2000
#define NMS_THR 0.7f
#define MASKW 48            // words covered by sparse conflict pairs (stop ~34)
#define SCAP 128            // cross-word pair cap per SOURCE word
#define ICAP 16             // in-word pair cap per word
#define NUNITS 312          // pair units: sum_{cbq<12} 4(cbq+1) = 312
#define NPROD 78            // producer blocks; 4 units each (312/4)
#define SLICE_STRIDE 260    // floats; 1040B: parts hit disjoint banks

// ---------------- ws layout ----------------
// 0      : bs       float4[8192]  128 KiB (sorted clipped boxes)
// 131072 : area     f32[8192]     32 KiB  (-1.0 marks invalid box)
// 163840 : ctrl     i32[64]       ([0..47] srcCnt, [48] overflow, [49] done)
// 164096 : inCnt    i32[64]
// 164352 : srcBuf   u32[48*128]   24 KiB  ((il<<13)|(wt<<6)|jl, bucket=src word)
// 188928 : inBuf    u32[48*16]    3 KiB   ((jl<<8)|il per in-word pair)

// ---------------------------------------------------------------------------
__device__ __forceinline__ float4 decode_clip_box(const float4 L, bool* valid) {
#pragma clang fp contract(off)
  float cy = L.x, cx = L.y, h = L.z, w = L.w;
  float y1 = cy - 0.5f * h;
  float x1 = cx - 0.5f * w;
  float y2 = cy + 0.5f * h;
  float x2 = cx + 0.5f * w;
  *valid = ((y2 - y1) > 16.0f) && ((x2 - x1) > 16.0f);
  float4 b;
  b.x = fminf(fmaxf(y1, 0.0f), 800.0f);
  b.y = fminf(fmaxf(x1, 0.0f), 800.0f);
  b.z = fminf(fmaxf(y2, 0.0f), 800.0f);
  b.w = fminf(fmaxf(x2, 0.0f), 800.0f);
  return b;
}

__device__ __forceinline__ float box_area(const float4 b) {
#pragma clang fp contract(off)
  return (b.z - b.x) * (b.w - b.y);   // clipped => always >= 0
}

__device__ __forceinline__ bool iou_gt_thr(const float4 a, float aa,
                                           const float4 b, float ab) {
#pragma clang fp contract(off)
  float iy = fminf(a.z, b.z) - fmaxf(a.x, b.x);
  float ix = fminf(a.w, b.w) - fmaxf(a.y, b.y);
  iy = fmaxf(iy, 0.0f);
  ix = fmaxf(ix, 0.0f);
  float inter = iy * ix;
  float uni = aa + ab - inter;
  // exact IEEE division: predicate must bit-match the numpy reference
  return (inter > 0.0f) && (uni > 0.0f) && ((inter / uni) > NMS_THR);
}

// Greedy within-word resolve from dense "who-I-suppress" (fallback only).
__device__ __forceinline__ ull resolve_word(ull dg, ull avail, int lane) {
  ull conflict = __ballot(((dg & avail) != 0ull) && ((avail >> lane) & 1ull));
  if (conflict == 0ull) return avail;
  ull dgT = 0ull;
  #pragma unroll
  for (int c = 0; c < 64; ++c) {
    ull tb = __ballot((dg >> c) & 1ull);
    if (lane == c) dgT = tb;
  }
  ull kept = avail;
  while (true) {                 // fixpoint == greedy (prefix-stabilization)
    bool sup = (dgT & kept) != 0ull;
    ull kn = avail & ~__ballot(sup);
    if (kn == kept) break;
    kept = kn;
  }
  return kept;
}

__device__ __forceinline__ unsigned aload(const unsigned* p) {
  return __hip_atomic_load(p, __ATOMIC_RELAXED, __HIP_MEMORY_SCOPE_AGENT);
}
__device__ __forceinline__ int aloadi(const int* p) {
  return __hip_atomic_load(p, __ATOMIC_RELAXED, __HIP_MEMORY_SCOPE_AGENT);
}

// ===========================================================================
// K1: rank + gather, fused.  GRID = N/8 = 1024 blocks (proven r19/r20).
// ===========================================================================
__global__ __launch_bounds__(256) void rankgather_kernel(
    const float* __restrict__ locs, const float* __restrict__ scores,
    float4* __restrict__ bs, float* __restrict__ area,
    int* __restrict__ ctrl, int* __restrict__ inCnt) {
  __shared__ float ssc[32 * SLICE_STRIDE];   // 33280 B, slices of 256 + pad
  __shared__ int sRank[8][33];               // +1 pad: conflict-free
  int tid = threadIdx.x, bid = blockIdx.x;
  if (bid == 0) {
    if (tid < 64) ctrl[tid] = 0;
    else if (tid < 128) inCnt[tid - 64] = 0;
  }
  const float4* locs4 = (const float4*)locs;
  for (int k = 0; k < 32; ++k) {
    int j = k * 256 + tid;                   // coalesced
    bool v; (void)decode_clip_box(locs4[j], &v);
    float s = v ? scores[j] : -__builtin_inff();
    ssc[(j >> 8) * SLICE_STRIDE + (j & 255)] = s;
  }
  __syncthreads();
  int boxOff = tid & 7;
  int part = tid >> 3;                       // 32 slices of 256 scores
  int i = bid * 8 + boxOff;
  float si = ssc[(i >> 8) * SLICE_STRIDE + (i & 255)];
  const float4* s4 = (const float4*)(ssc + part * SLICE_STRIDE);
  int j0 = part * 256;
  int cnt = 0;
  // j precedes i <=> s_j > s_i || (s_j == s_i && j < i)  (stable descending)
  for (int q = 0; q < 64; ++q) {
    float4 v = s4[q];                        // 8 distinct banksets: no conflict
    int j = j0 + 4 * q;
    cnt += (v.x > si) || ((v.x == si) & ((j + 0) < i));
    cnt += (v.y > si) || ((v.y == si) & ((j + 1) < i));
    cnt += (v.z > si) || ((v.z == si) & ((j + 2) < i));
    cnt += (v.w > si) || ((v.w == si) & ((j + 3) < i));
  }
  sRank[boxOff][part] = cnt;
  __syncthreads();
  if (tid < 8) {
    int r = 0;
    #pragma unroll
    for (int p = 0; p < 32; ++p) r += sRank[tid][p];
    int ig = bid * 8 + tid;
    bool v;
    float4 b = decode_clip_box(locs4[ig], &v);
    bs[r] = b;
    area[r] = v ? box_area(b) : -1.0f;       // sign encodes validity
  }
}

// ===========================================================================
// K2: pairs (blocks 1..78, 4 units each) + scan (block 0), single dispatch.
// r21 change: 312 -> 78 producer blocks.  The done-counter handoff was a
// 312-deep serialized same-line atomic RMW (~13us tail); now 78.
// ===========================================================================
__global__ __launch_bounds__(256) void pairscan_kernel(
    const float4* __restrict__ bs, const float* __restrict__ area,
    int* __restrict__ ctrl, int* __restrict__ inCnt,
    unsigned* __restrict__ srcBuf, unsigned* __restrict__ inBuf,
    float* __restrict__ out) {
  __shared__ __align__(16) char smem[35840];
  int tid = threadIdx.x, bid = blockIdx.x;

  if (bid > 0) {
    // ---------------- producer: units 4*(bid-1) .. 4*(bid-1)+3 ----------
    float4* sb = (float4*)smem;               // [4][64]
    float*  sa = (float*)(smem + 4096);       // [4][64]
    int lane = tid & 63, cq = tid >> 6;
    for (int k4 = 0; k4 < 4; ++k4) {
      int u = (bid - 1) * 4 + k4;
      int cbq = 0;                            // largest c with 2c(c+1) <= u
      while (2 * (cbq + 1) * (cbq + 2) <= u) ++cbq;
      int rb = u - 2 * cbq * (cbq + 1);
      int cb = cbq * 4 + cq;
      int j0 = cb * 64;
      __syncthreads();                        // WAR: prev unit's reads done
      sb[cq * 64 + lane] = bs[j0 + lane];
      sa[cq * 64 + lane] = area[j0 + lane];
      int i = rb * 64 + lane;
      float4 r = bs[i];
      float ai = area[i];
      __syncthreads();
      if (cb >= rb && ai >= 0.0f) {           // invalid i never pairs
        ull bits = 0;
        for (int c = 0; c < 64; ++c) {
          if ((j0 + c) > i && sa[cq * 64 + c] >= 0.0f &&
              iou_gt_thr(r, ai, sb[cq * 64 + c], sa[cq * 64 + c]))
            bits |= 1ull << c;
        }
        int n = (int)__popcll(bits);
        if (n) {
          if (cb == rb) {                     // in-word pairs (bucket = word)
            int base = atomicAdd(&inCnt[cb], n);
            if (base + n > ICAP) {
              __hip_atomic_store(&ctrl[48], 1, __ATOMIC_RELAXED,
                                 __HIP_MEMORY_SCOPE_AGENT);
            } else {
              int k = base;
              while (bits) {
                int c = (int)__builtin_ctzll(bits); bits &= bits - 1;
                __hip_atomic_store(&inBuf[cb * ICAP + k++],
                                   ((unsigned)c << 8) | (unsigned)lane,
                                   __ATOMIC_RELAXED, __HIP_MEMORY_SCOPE_AGENT);
              }
            }
          } else {                            // cross pairs, bucket = SOURCE rb
            int base = atomicAdd(&ctrl[rb], n);
            if (base + n > SCAP) {
              __hip_atomic_store(&ctrl[48], 1, __ATOMIC_RELAXED,
                                 __HIP_MEMORY_SCOPE_AGENT);
            } else {
              int k = base;
              while (bits) {
                int c = (int)__builtin_ctzll(bits); bits &= bits - 1;
                // (il<<13) | (wt<<6) | jl
                __hip_atomic_store(&srcBuf[rb * SCAP + k++],
                                   ((unsigned)lane << 13) | ((unsigned)cb << 6) |
                                       (unsigned)c,
                                   __ATOMIC_RELAXED, __HIP_MEMORY_SCOPE_AGENT);
              }
            }
          }
        }
      }
    }
    __syncthreads();   // drains vmcnt(0): all units' stores acked at LLC
    if (tid == 0)
      __hip_atomic_fetch_add(&ctrl[49], 1, __ATOMIC_RELAXED,
                             __HIP_MEMORY_SCOPE_AGENT);
    return;
  }

  // ---------------- scan (block 0) ----------------
  unsigned (*sSrc)[SCAP] = (unsigned(*)[SCAP])(smem + 0);       // 24 KiB
  unsigned (*sIn)[ICAP]  = (unsigned(*)[ICAP])(smem + 24576);   // 3 KiB
  int*  sSCnt     = (int*)(smem + 27648);
  int*  sICnt     = (int*)(smem + 27840);
  ull*  sRemv     = (ull*)(smem + 28032);      // 1 KiB
  u16*  sKeptList = (u16*)(smem + 29056);      // 4000 B
  float4* sWB     = (float4*)(smem + 33056);
  float*  sWA     = (float*)(smem + 34080);
  ull*  sSupW     = (ull*)(smem + 34336);
  int*  sCtl      = (int*)(smem + 34344);      // [0]=base [1]=stop [2]=over

  // pre-spin: sRemv from area sign, 8-deep batched loads (proven r20)
  {
    int wave = tid >> 6, lane = tid & 63;
    for (int b = 0; b < 4; ++b) {
      float av[8];
      #pragma unroll
      for (int q = 0; q < 8; ++q)
        av[q] = area[(wave + (b * 8 + q) * 4) * 64 + lane];
      #pragma unroll
      for (int q = 0; q < 8; ++q) {
        ull inv = __ballot(av[q] < 0.0f);
        if (lane == 0) sRemv[wave + (b * 8 + q) * 4] = inv;
      }
    }
  }
  if (tid == 254) sCtl[0] = 0;
  if (tid == 253) sCtl[1] = 0;

  // wait for all producer blocks (relaxed agent poll, proven r12..r20)
  if (tid == 0) {
    while (__hip_atomic_load(&ctrl[49], __ATOMIC_RELAXED,
                             __HIP_MEMORY_SCOPE_AGENT) < NPROD)
      __builtin_amdgcn_s_sleep(2);
  }
  __syncthreads();

  // counts via agent loads (few); payload via plain vectorized loads (r20)
  if (tid < MASKW) { sSCnt[tid] = aloadi(&ctrl[tid]); sICnt[tid] = aloadi(&inCnt[tid]); }
  if (tid == 255) sCtl[2] = aloadi(&ctrl[48]);
  {
    const uint4* src4 = (const uint4*)srcBuf;          // 1536 uint4
    uint4* dst4 = (uint4*)sSrc;
    #pragma unroll
    for (int k = 0; k < 6; ++k) dst4[tid + k * 256] = src4[tid + k * 256];
    const uint4* in4 = (const uint4*)inBuf;            // 192 uint4
    if (tid < 192) ((uint4*)sIn)[tid] = in4[tid];
  }
  __syncthreads();

  int sOver = sCtl[2];
  // ---- sparse masked phase (wave 0 only; no shfl/reduce in the loop)
  if (!sOver && tid < 64) {
    int lane = tid;
    int base = 0;
    for (int w = 0; w < MASKW; ++w) {
      ull avail = ~sRemv[w];                   // in-order LDS: sees all ORs
      int cnI = sICnt[w];
      ull kept;
      if (cnI == 0) {
        kept = avail;
      } else {
        ull dgT = 0ull;                        // my in-word suppressors
        for (int k = 0; k < cnI; ++k) {
          unsigned p = sIn[w][k];              // uniform LDS read
          int il = (int)(p & 63u);
          int jl = (int)(p >> 8) & 63;
          if (lane == jl) dgT |= 1ull << il;
        }
        ull cf = __ballot(((dgT & avail) != 0ull) && ((avail >> lane) & 1ull));
        if (cf == 0ull) {
          kept = avail;
        } else {
          kept = avail;
          while (true) {                       // fixpoint == greedy
            bool sup = (dgT & kept) != 0ull;
            ull kn = avail & ~__ballot(sup);
            if (kn == kept) break;
            kept = kn;
          }
        }
      }
      if ((kept >> lane) & 1ull) {
        int rank = base + (int)__popcll(kept & ((1ull << lane) - 1ull));
        if (rank < NPOST) sKeptList[rank] = (u16)(w * 64 + lane);
      }
      base += (int)__popcll(kept);
      if (base >= NPOST) break;                // ranks >=2000 never emitted
      // eager push-forward: lane-parallel, no reduction
      int cnS = sSCnt[w];
      for (int k = lane; k < cnS; k += 64) {
        unsigned p = sSrc[w][k];
        int il = (int)(p >> 13) & 63;
        if ((kept >> il) & 1ull) {
          int wt = (int)(p >> 6) & 127;
          atomicOr(&sRemv[wt], 1ull << (p & 63u));   // LDS atomic
        }
      }
    }
    if (lane == 0) { sCtl[0] = base; if (base >= NPOST) sCtl[1] = 1; }
  }
  __syncthreads();

  // ---- dense fallback (correctness only; not hit by the bench input)
  int startW = sOver ? 0 : MASKW;
  if (!sCtl[1]) {
    for (int w = startW; w < NWORDS; ++w) {
      if (tid < 64) { sWB[tid] = bs[w * 64 + tid]; sWA[tid] = area[w * 64 + tid]; }
      if (tid == 0) *sSupW = sRemv[w];
      __syncthreads();
      int nk = sCtl[0];
      int c = tid & 63;
      for (int k0 = tid >> 6; k0 < nk; k0 += 4) {   // wave per kept box
        int ki = sKeptList[k0];
        float4 kb = bs[ki];                         // uniform load
        bool s = iou_gt_thr(kb, area[ki], sWB[c], sWA[c]);
        ull bits = __ballot(s);
        if (c == 0 && bits) atomicOr(sSupW, bits);
      }
      __syncthreads();
      if (tid < 64) {
        int lane = tid;
        float4 bm = sWB[lane];
        float am = sWA[lane];
        ull dg = 0;
        if (am >= 0.0f) {
          for (int cc = lane + 1; cc < 64; ++cc)
            if (sWA[cc] >= 0.0f && iou_gt_thr(bm, am, sWB[cc], sWA[cc]))
              dg |= 1ull << cc;
        }
        ull avail = ~*sSupW;
        ull kept = resolve_word(dg, avail, lane);
        int base = sCtl[0];
        if ((kept >> lane) & 1ull) {
          int rank = base + (int)__popcll(kept & ((1ull << lane) - 1ull));
          if (rank < NPOST) sKeptList[rank] = (u16)(w * 64 + lane);
        }
        if (lane == 0) {
          int nb = base + (int)__popcll(kept);
          sCtl[0] = nb;
          if (nb >= NPOST) sCtl[1] = 1;
        }
      }
      __syncthreads();
      if (sCtl[1]) break;
    }
  }

  __syncthreads();
  int total = sCtl[0];
  if (total > NPOST) total = NPOST;
  for (int r = tid; r < NPOST; r += 256) {
    float4 v = make_float4(0.0f, 0.0f, 0.0f, 0.0f);
    if (r < total) v = bs[sKeptList[r]];
    reinterpret_cast<float4*>(out)[r] = v;
  }
  // beacon: self-diagnose a repeat failure (never fires on a healthy run)
  if (total == 0 && tid == 0)
    out[0] = 5.0e9f + (float)sCtl[2] * 1.0e8f;
}

// ---------------------------------------------------------------------------
extern "C" void kernel_launch(void* const* d_in, const int* in_sizes, int n_in,
                              void* d_out, int out_size, void* d_ws, size_t ws_size,
                              hipStream_t stream) {
  const float* locs   = (const float*)d_in[0];   // (8192,4) cy,cx,h,w
  const float* scores = (const float*)d_in[1];   // (8192,)

  char* ws = (char*)d_ws;
  float4*   bs       = (float4*)(ws + 0);
  float*    area     = (float*)(ws + 131072);
  int*      ctrl     = (int*)(ws + 163840);
  int*      inCnt    = (int*)(ws + 164096);
  unsigned* srcBuf   = (unsigned*)(ws + 164352);
  unsigned* inBuf    = (unsigned*)(ws + 188928);

  rankgather_kernel<<<N / 8, 256, 0, stream>>>(locs, scores, bs, area, ctrl, inCnt);
  pairscan_kernel<<<NPROD + 1, 256, 0, stream>>>(
      bs, area, ctrl, inCnt, srcBuf, inBuf, (float*)d_out);
}

// Round 22
// 60.875 us; speedup vs baseline: 1.6632x; 1.6632x over previous
//
#include <hip/hip_runtime.h>
#include <cstdint>
#include <cstddef>

typedef unsigned long long ull;
typedef unsigned short u16;

#define N 8192
#define NWORDS 128          // 8192 / 64
#define NPOST 2000
#define NMS_THR 0.7f
#define MASKW 48            // words covered by sparse conflict pairs (stop ~34)
#define SCAP 128            // cross-word pair cap per SOURCE word
#define ICAP 16             // in-word pair cap per word
#define NUNITS 312          // pair units: sum_{cbq<12} 4(cbq+1) = 312
#define SLICE_STRIDE 260    // floats; 1040B: parts hit disjoint banks

// ---------------- ws layout ----------------
// 0      : bs       float4[8192]  128 KiB (sorted clipped boxes)
// 131072 : area     f32[8192]     32 KiB  (-1.0 marks invalid box)
// 163840 : ctrl     i32[64]       ([0..47] srcCnt, [48] overflow)
// 164096 : inCnt    i32[64]
// 164352 : srcBuf   u32[48*128]   24 KiB  ((il<<13)|(wt<<6)|jl, bucket=src word)
// 188928 : inBuf    u32[48*16]    3 KiB   ((jl<<8)|il per in-word pair)

// ---------------------------------------------------------------------------
__device__ __forceinline__ float4 decode_clip_box(const float4 L, bool* valid) {
#pragma clang fp contract(off)
  float cy = L.x, cx = L.y, h = L.z, w = L.w;
  float y1 = cy - 0.5f * h;
  float x1 = cx - 0.5f * w;
  float y2 = cy + 0.5f * h;
  float x2 = cx + 0.5f * w;
  *valid = ((y2 - y1) > 16.0f) && ((x2 - x1) > 16.0f);
  float4 b;
  b.x = fminf(fmaxf(y1, 0.0f), 800.0f);
  b.y = fminf(fmaxf(x1, 0.0f), 800.0f);
  b.z = fminf(fmaxf(y2, 0.0f), 800.0f);
  b.w = fminf(fmaxf(x2, 0.0f), 800.0f);
  return b;
}

__device__ __forceinline__ float box_area(const float4 b) {
#pragma clang fp contract(off)
  return (b.z - b.x) * (b.w - b.y);   // clipped => always >= 0
}

__device__ __forceinline__ bool iou_gt_thr(const float4 a, float aa,
                                           const float4 b, float ab) {
#pragma clang fp contract(off)
  float iy = fminf(a.z, b.z) - fmaxf(a.x, b.x);
  float ix = fminf(a.w, b.w) - fmaxf(a.y, b.y);
  iy = fmaxf(iy, 0.0f);
  ix = fmaxf(ix, 0.0f);
  float inter = iy * ix;
  float uni = aa + ab - inter;
  // exact IEEE division: predicate must bit-match the numpy reference
  return (inter > 0.0f) && (uni > 0.0f) && ((inter / uni) > NMS_THR);
}

// Greedy within-word resolve from dense "who-I-suppress" (fallback only).
__device__ __forceinline__ ull resolve_word(ull dg, ull avail, int lane) {
  ull conflict = __ballot(((dg & avail) != 0ull) && ((avail >> lane) & 1ull));
  if (conflict == 0ull) return avail;
  ull dgT = 0ull;
  #pragma unroll
  for (int c = 0; c < 64; ++c) {
    ull tb = __ballot((dg >> c) & 1ull);
    if (lane == c) dgT = tb;
  }
  ull kept = avail;
  while (true) {                 // fixpoint == greedy (prefix-stabilization)
    bool sup = (dgT & kept) != 0ull;
    ull kn = avail & ~__ballot(sup);
    if (kn == kept) break;
    kept = kn;
  }
  return kept;
}

// ===========================================================================
// K1: rank + gather, fused.  GRID = N/8 = 1024 blocks (proven r19/r20).
// Block 0 zeroes K2's counters (stream order -> visible to K2).
// ===========================================================================
__global__ __launch_bounds__(256) void rankgather_kernel(
    const float* __restrict__ locs, const float* __restrict__ scores,
    float4* __restrict__ bs, float* __restrict__ area,
    int* __restrict__ ctrl, int* __restrict__ inCnt) {
  __shared__ float ssc[32 * SLICE_STRIDE];   // 33280 B, slices of 256 + pad
  __shared__ int sRank[8][33];               // +1 pad: conflict-free
  int tid = threadIdx.x, bid = blockIdx.x;
  if (bid == 0) {
    if (tid < 64) ctrl[tid] = 0;
    else if (tid < 128) inCnt[tid - 64] = 0;
  }
  const float4* locs4 = (const float4*)locs;
  for (int k = 0; k < 32; ++k) {
    int j = k * 256 + tid;                   // coalesced
    bool v; (void)decode_clip_box(locs4[j], &v);
    float s = v ? scores[j] : -__builtin_inff();
    ssc[(j >> 8) * SLICE_STRIDE + (j & 255)] = s;
  }
  __syncthreads();
  int boxOff = tid & 7;
  int part = tid >> 3;                       // 32 slices of 256 scores
  int i = bid * 8 + boxOff;
  float si = ssc[(i >> 8) * SLICE_STRIDE + (i & 255)];
  const float4* s4 = (const float4*)(ssc + part * SLICE_STRIDE);
  int j0 = part * 256;
  int cnt = 0;
  // j precedes i <=> s_j > s_i || (s_j == s_i && j < i)  (stable descending)
  for (int q = 0; q < 64; ++q) {
    float4 v = s4[q];                        // 8 distinct banksets: no conflict
    int j = j0 + 4 * q;
    cnt += (v.x > si) || ((v.x == si) & ((j + 0) < i));
    cnt += (v.y > si) || ((v.y == si) & ((j + 1) < i));
    cnt += (v.z > si) || ((v.z == si) & ((j + 2) < i));
    cnt += (v.w > si) || ((v.w == si) & ((j + 3) < i));
  }
  sRank[boxOff][part] = cnt;
  __syncthreads();
  if (tid < 8) {
    int r = 0;
    #pragma unroll
    for (int p = 0; p < 32; ++p) r += sRank[tid][p];
    int ig = bid * 8 + tid;
    bool v;
    float4 b = decode_clip_box(locs4[ig], &v);
    bs[r] = b;
    area[r] = v ? box_area(b) : -1.0f;       // sign encodes validity
  }
}

// ===========================================================================
// K2: sparse conflict pairs, standalone (r9-proven ~4us wall).  One unit per
// block; PLAIN stores/atomics — the kernel boundary provides visibility.
// ===========================================================================
__global__ __launch_bounds__(256) void pairs_kernel(
    const float4* __restrict__ bs, const float* __restrict__ area,
    int* __restrict__ ctrl, int* __restrict__ inCnt,
    unsigned* __restrict__ srcBuf, unsigned* __restrict__ inBuf) {
  __shared__ float4 sb[4][64];
  __shared__ float  sa[4][64];
  int tid = threadIdx.x;
  int u = blockIdx.x;
  int cbq = 0;                              // largest c with 2c(c+1) <= u
  while (2 * (cbq + 1) * (cbq + 2) <= u) ++cbq;
  int rb = u - 2 * cbq * (cbq + 1);
  int lane = tid & 63, cq = tid >> 6;
  int cb = cbq * 4 + cq;
  int j0 = cb * 64;
  sb[cq][lane] = bs[j0 + lane];
  sa[cq][lane] = area[j0 + lane];
  int i = rb * 64 + lane;
  float4 r = bs[i];
  float ai = area[i];
  __syncthreads();
  if (cb < rb || ai < 0.0f) return;         // invalid i never pairs
  ull bits = 0;
  for (int c = 0; c < 64; ++c) {
    if ((j0 + c) > i && sa[cq][c] >= 0.0f &&
        iou_gt_thr(r, ai, sb[cq][c], sa[cq][c]))
      bits |= 1ull << c;
  }
  int n = (int)__popcll(bits);
  if (!n) return;
  if (cb == rb) {                           // in-word pairs (bucket = word)
    int base = atomicAdd(&inCnt[cb], n);
    if (base + n > ICAP) { ctrl[48] = 1; return; }
    int k = base;
    while (bits) {
      int c = (int)__builtin_ctzll(bits); bits &= bits - 1;
      inBuf[cb * ICAP + k++] = ((unsigned)c << 8) | (unsigned)lane;
    }
  } else {                                  // cross pairs, bucket = SOURCE rb
    int base = atomicAdd(&ctrl[rb], n);
    if (base + n > SCAP) { ctrl[48] = 1; return; }
    int k = base;
    while (bits) {
      int c = (int)__builtin_ctzll(bits); bits &= bits - 1;
      srcBuf[rb * SCAP + k++] =             // (il<<13) | (wt<<6) | jl
          ((unsigned)lane << 13) | ((unsigned)cb << 6) | (unsigned)c;
    }
  }
}

// ===========================================================================
// K3: greedy scan, standalone single block (r20 block-0 path, spin removed,
// plain loads everywhere — kernel boundary gives fresh data).
// ===========================================================================
__global__ __launch_bounds__(256) void scan_kernel(
    const float4* __restrict__ bs, const float* __restrict__ area,
    const int* __restrict__ ctrl, const int* __restrict__ inCnt,
    const unsigned* __restrict__ srcBuf, const unsigned* __restrict__ inBuf,
    float* __restrict__ out) {
  __shared__ __align__(16) char smem[35840];
  int tid = threadIdx.x;

  unsigned (*sSrc)[SCAP] = (unsigned(*)[SCAP])(smem + 0);       // 24 KiB
  unsigned (*sIn)[ICAP]  = (unsigned(*)[ICAP])(smem + 24576);   // 3 KiB
  int*  sSCnt     = (int*)(smem + 27648);
  int*  sICnt     = (int*)(smem + 27840);
  ull*  sRemv     = (ull*)(smem + 28032);      // 1 KiB
  u16*  sKeptList = (u16*)(smem + 29056);      // 4000 B
  float4* sWB     = (float4*)(smem + 33056);
  float*  sWA     = (float*)(smem + 34080);
  ull*  sSupW     = (ull*)(smem + 34336);
  int*  sCtl      = (int*)(smem + 34344);      // [0]=base [1]=stop [2]=over

  // sRemv from area sign, 8-deep batched loads (proven r20)
  {
    int wave = tid >> 6, lane = tid & 63;
    for (int b = 0; b < 4; ++b) {
      float av[8];
      #pragma unroll
      for (int q = 0; q < 8; ++q)
        av[q] = area[(wave + (b * 8 + q) * 4) * 64 + lane];
      #pragma unroll
      for (int q = 0; q < 8; ++q) {
        ull inv = __ballot(av[q] < 0.0f);
        if (lane == 0) sRemv[wave + (b * 8 + q) * 4] = inv;
      }
    }
  }
  if (tid == 254) sCtl[0] = 0;
  if (tid == 253) sCtl[1] = 0;
  if (tid < MASKW) { sSCnt[tid] = ctrl[tid]; sICnt[tid] = inCnt[tid]; }
  if (tid == 255) sCtl[2] = ctrl[48];
  {
    const uint4* src4 = (const uint4*)srcBuf;          // 1536 uint4
    uint4* dst4 = (uint4*)sSrc;
    #pragma unroll
    for (int k = 0; k < 6; ++k) dst4[tid + k * 256] = src4[tid + k * 256];
    const uint4* in4 = (const uint4*)inBuf;            // 192 uint4
    if (tid < 192) ((uint4*)sIn)[tid] = in4[tid];
  }
  __syncthreads();

  int sOver = sCtl[2];
  // ---- sparse masked phase (wave 0 only; no shfl/reduce in the loop)
  if (!sOver && tid < 64) {
    int lane = tid;
    int base = 0;
    for (int w = 0; w < MASKW; ++w) {
      ull avail = ~sRemv[w];                   // in-order LDS: sees all ORs
      int cnI = sICnt[w];
      ull kept;
      if (cnI == 0) {
        kept = avail;
      } else {
        ull dgT = 0ull;                        // my in-word suppressors
        for (int k = 0; k < cnI; ++k) {
          unsigned p = sIn[w][k];              // uniform LDS read
          int il = (int)(p & 63u);
          int jl = (int)(p >> 8) & 63;
          if (lane == jl) dgT |= 1ull << il;
        }
        ull cf = __ballot(((dgT & avail) != 0ull) && ((avail >> lane) & 1ull));
        if (cf == 0ull) {
          kept = avail;
        } else {
          kept = avail;
          while (true) {                       // fixpoint == greedy
            bool sup = (dgT & kept) != 0ull;
            ull kn = avail & ~__ballot(sup);
            if (kn == kept) break;
            kept = kn;
          }
        }
      }
      if ((kept >> lane) & 1ull) {
        int rank = base + (int)__popcll(kept & ((1ull << lane) - 1ull));
        if (rank < NPOST) sKeptList[rank] = (u16)(w * 64 + lane);
      }
      base += (int)__popcll(kept);
      if (base >= NPOST) break;                // ranks >=2000 never emitted
      // eager push-forward: lane-parallel, no reduction
      int cnS = sSCnt[w];
      for (int k = lane; k < cnS; k += 64) {
        unsigned p = sSrc[w][k];
        int il = (int)(p >> 13) & 63;
        if ((kept >> il) & 1ull) {
          int wt = (int)(p >> 6) & 127;
          atomicOr(&sRemv[wt], 1ull << (p & 63u));   // LDS atomic
        }
      }
    }
    if (lane == 0) { sCtl[0] = base; if (base >= NPOST) sCtl[1] = 1; }
  }
  __syncthreads();

  // ---- dense fallback (correctness only; not hit by the bench input)
  int startW = sOver ? 0 : MASKW;
  if (!sCtl[1]) {
    for (int w = startW; w < NWORDS; ++w) {
      if (tid < 64) { sWB[tid] = bs[w * 64 + tid]; sWA[tid] = area[w * 64 + tid]; }
      if (tid == 0) *sSupW = sRemv[w];
      __syncthreads();
      int nk = sCtl[0];
      int c = tid & 63;
      for (int k0 = tid >> 6; k0 < nk; k0 += 4) {   // wave per kept box
        int ki = sKeptList[k0];
        float4 kb = bs[ki];                         // uniform load
        bool s = iou_gt_thr(kb, area[ki], sWB[c], sWA[c]);
        ull bits = __ballot(s);
        if (c == 0 && bits) atomicOr(sSupW, bits);
      }
      __syncthreads();
      if (tid < 64) {
        int lane = tid;
        float4 bm = sWB[lane];
        float am = sWA[lane];
        ull dg = 0;
        if (am >= 0.0f) {
          for (int cc = lane + 1; cc < 64; ++cc)
            if (sWA[cc] >= 0.0f && iou_gt_thr(bm, am, sWB[cc], sWA[cc]))
              dg |= 1ull << cc;
        }
        ull avail = ~*sSupW;
        ull kept = resolve_word(dg, avail, lane);
        int base = sCtl[0];
        if ((kept >> lane) & 1ull) {
          int rank = base + (int)__popcll(kept & ((1ull << lane) - 1ull));
          if (rank < NPOST) sKeptList[rank] = (u16)(w * 64 + lane);
        }
        if (lane == 0) {
          int nb = base + (int)__popcll(kept);
          sCtl[0] = nb;
          if (nb >= NPOST) sCtl[1] = 1;
        }
      }
      __syncthreads();
      if (sCtl[1]) break;
    }
  }

  __syncthreads();
  int total = sCtl[0];
  if (total > NPOST) total = NPOST;
  for (int r = tid; r < NPOST; r += 256) {
    float4 v = make_float4(0.0f, 0.0f, 0.0f, 0.0f);
    if (r < total) v = bs[sKeptList[r]];
    reinterpret_cast<float4*>(out)[r] = v;
  }
  // beacon: self-diagnose a repeat failure (never fires on a healthy run)
  if (total == 0 && tid == 0)
    out[0] = 5.0e9f + (float)sCtl[2] * 1.0e8f;
}

// ---------------------------------------------------------------------------
extern "C" void kernel_launch(void* const* d_in, const int* in_sizes, int n_in,
                              void* d_out, int out_size, void* d_ws, size_t ws_size,
                              hipStream_t stream) {
  const float* locs   = (const float*)d_in[0];   // (8192,4) cy,cx,h,w
  const float* scores = (const float*)d_in[1];   // (8192,)

  char* ws = (char*)d_ws;
  float4*   bs       = (float4*)(ws + 0);
  float*    area     = (float*)(ws + 131072);
  int*      ctrl     = (int*)(ws + 163840);
  int*      inCnt    = (int*)(ws + 164096);
  unsigned* srcBuf   = (unsigned*)(ws + 164352);
  unsigned* inBuf    = (unsigned*)(ws + 188928);

  rankgather_kernel<<<N / 8, 256, 0, stream>>>(locs, scores, bs, area, ctrl, inCnt);
  pairs_kernel<<<NUNITS, 256, 0, stream>>>(bs, area, ctrl, inCnt, srcBuf, inBuf);
  scan_kernel<<<1, 256, 0, stream>>>(bs, area, ctrl, inCnt, srcBuf, inBuf,
                                     (float*)d_out);
}